// Round 1
// baseline (859.258 us; speedup 1.0000x reference)
//
#include <hip/hip_runtime.h>
#include <hip/hip_bf16.h>
#include <stdint.h>

// CubicModel: out = feats(feats(x)@W0^T + b0)@W1^T + b1
// feats(v) = [v, v_i*v_j (i<=j upper-tri row-major), v^3], d=512, K=132352
//
// Strategy: bf16 MFMA GEMM (threshold 0.117 = 8 bf16-ulp budget).
//  - featgen writes bf16 features to ws (chunked if ws small)
//  - gemm: BM=512 (W read once), BN=128, BK=32, split-K + f32 atomics

#define D_IN      512
#define BATCH     512
#define K_TOT     132352
#define QUAD_BASE 512
#define CUBE_BASE 131840
#define BN        128
#define BK        32

typedef __attribute__((ext_vector_type(8))) __bf16 bf16x8;
typedef __attribute__((ext_vector_type(4))) float  f32x4;

__device__ __forceinline__ uint16_t f2bf(float f) {
    union { float f; uint32_t u; } v; v.f = f;
    uint32_t u = v.u;
    return (uint16_t)((u + 0x7FFFu + ((u >> 16) & 1u)) >> 16);   // RNE
}

// ---------------- feature generation ----------------
// grid.x = 514: blocks 0..511 = quad row i, 512 = linear, 513 = cube
// writes bf16 feats for feature window [k0, k0+ext) into dst[b][k-k0], row stride ldd
__global__ __launch_bounds__(256) void featgen(const float* __restrict__ src,
                                               uint16_t* __restrict__ dst,
                                               int k0, int ext, int ldd)
{
    const int blk = blockIdx.x;
    const int tid = threadIdx.x;
    const int kend = k0 + ext;

    if (blk < 512) {                       // quad row i: features base..base+(512-i)
        const int i = blk;
        const long long base = (long long)QUAD_BASE + (long long)i * 512 - (long long)i * (i - 1) / 2;
        long long jsL = (long long)i + ((long long)k0 > base ? (long long)k0 - base : 0);
        long long jeL = (long long)i + ((long long)(512 - i) < (long long)kend - base
                                        ? (long long)(512 - i) : (long long)kend - base);
        int j_start = (int)jsL, j_end = (int)jeL;
        if (j_start >= j_end) return;
        const int off = (int)(base - k0) - i;          // dst col = off + j
        for (int b = 0; b < BATCH; ++b) {
            const float* row = src + (size_t)b * D_IN;
            const float xi = row[i];
            uint16_t* drow = dst + (size_t)b * ldd;
            for (int j = j_start + tid; j < j_end; j += 256)
                drow[off + j] = f2bf(xi * row[j]);
        }
    } else if (blk == 512) {               // linear region [0, 512)
        int klo = k0 > 0 ? k0 : 0;
        int khi = kend < 512 ? kend : 512;
        if (klo >= khi) return;
        for (int b = 0; b < BATCH; ++b) {
            const float* row = src + (size_t)b * D_IN;
            uint16_t* drow = dst + (size_t)b * ldd;
            for (int k = klo + tid; k < khi; k += 256)
                drow[k - k0] = f2bf(row[k]);
        }
    } else {                               // cube region [CUBE_BASE, CUBE_BASE+512)
        int tlo = k0 - CUBE_BASE > 0 ? k0 - CUBE_BASE : 0;
        int thi = kend - CUBE_BASE < 512 ? kend - CUBE_BASE : 512;
        if (tlo >= thi) return;
        for (int b = 0; b < BATCH; ++b) {
            const float* row = src + (size_t)b * D_IN;
            uint16_t* drow = dst + (size_t)b * ldd + (CUBE_BASE - k0);
            for (int t = tlo + tid; t < thi; t += 256) {
                float xv = row[t];
                drow[t] = f2bf(xv * xv * xv);
            }
        }
    }
}

// ---------------- split-K GEMM ----------------
// C[512][ldc] += A_bf16[512][lda(window kext)] * W_f32[n][K_TOT]^T  (+bias once)
// grid = (N/BN, S). 1024 threads = 16 waves, 8(m) x 2(n), wave tile 64x64.
__global__ __launch_bounds__(1024) void gemm_split(
    const uint16_t* __restrict__ A, int lda,
    const float* __restrict__ W, int k0, int kext,
    float* __restrict__ C, int ldc,
    const float* __restrict__ bias, int addbias, int split_steps)
{
    __shared__ uint16_t Al[512 * BK];   // 32 KiB  [row][k]
    __shared__ uint16_t Bl[BN * BK];    //  8 KiB  [n][k]

    const int tid  = threadIdx.x;
    const int lane = tid & 63;
    const int wave = tid >> 6;          // 0..15
    const int wm   = wave >> 1;         // 0..7 : rows wm*64
    const int wn   = wave & 1;          // 0..1 : cols wn*64
    const int n0   = blockIdx.x * BN;
    const int ks   = blockIdx.y;

    const int kbeg = ks * split_steps * BK;
    const int kend = min(kext, kbeg + split_steps * BK);
    if (kbeg >= kend) return;           // ks==0 always has work -> bias safe

    f32x4 acc[4][4] = {};

    const int fr = lane & 15;           // fragment row (A:m, B:n)
    const int fk = (lane >> 4) * 8;     // fragment k offset

    for (int kk = kbeg; kk < kend; kk += BK) {
        __syncthreads();
        // stage A: 512 rows x 32 bf16 (64B/row = 4 x 16B granules), 2048 granules
        #pragma unroll
        for (int it = 0; it < 2; ++it) {
            int g = it * 1024 + tid;
            int row = g >> 2, kq = (g & 3) * 8;
            uint4 v = *(const uint4*)(A + (size_t)row * lda + kk + kq);
            *(uint4*)(&Al[row * BK + kq]) = v;
        }
        // stage B: 128 rows x 32 f32 -> bf16, 1024 granules of 4 floats
        {
            int row = tid >> 3, kq = (tid & 7) * 4;
            const float* wp = W + (size_t)(n0 + row) * K_TOT + k0 + kk + kq;
            float4 w4 = *(const float4*)wp;
            ushort4 h4;
            h4.x = f2bf(w4.x); h4.y = f2bf(w4.y); h4.z = f2bf(w4.z); h4.w = f2bf(w4.w);
            *(ushort4*)(&Bl[row * BK + kq]) = h4;
        }
        __syncthreads();

        bf16x8 a[4];
        #pragma unroll
        for (int mf = 0; mf < 4; ++mf)
            a[mf] = *(const bf16x8*)(&Al[(wm * 64 + mf * 16 + fr) * BK + fk]);
        #pragma unroll
        for (int nf = 0; nf < 4; ++nf) {
            bf16x8 b = *(const bf16x8*)(&Bl[(wn * 64 + nf * 16 + fr) * BK + fk]);
            #pragma unroll
            for (int mf = 0; mf < 4; ++mf)
                acc[mf][nf] = __builtin_amdgcn_mfma_f32_16x16x32_bf16(a[mf], b, acc[mf][nf], 0, 0, 0);
        }
    }

    // epilogue: C/D layout col=lane&15, row=(lane>>4)*4+reg  [m89-verified]
    const bool dob = (addbias != 0) && (ks == 0);
    const int rbase = wm * 64 + (lane >> 4) * 4;
    const int cbase = n0 + wn * 64 + (lane & 15);
    #pragma unroll
    for (int nf = 0; nf < 4; ++nf) {
        const int col = cbase + nf * 16;
        const float bv = dob ? bias[col] : 0.0f;
        #pragma unroll
        for (int mf = 0; mf < 4; ++mf) {
            const int row = rbase + mf * 16;
            #pragma unroll
            for (int r = 0; r < 4; ++r)
                unsafeAtomicAdd(&C[(size_t)(row + r) * ldc + col], acc[mf][nf][r] + bv);
        }
    }
}

// ---------------- host ----------------
extern "C" void kernel_launch(void* const* d_in, const int* in_sizes, int n_in,
                              void* d_out, int out_size, void* d_ws, size_t ws_size,
                              hipStream_t stream)
{
    const float* x  = (const float*)d_in[0];
    const float* W0 = (const float*)d_in[1];
    const float* b0 = (const float*)d_in[2];
    const float* W1 = (const float*)d_in[3];
    const float* b1 = (const float*)d_in[4];
    float* out = (float*)d_out;

    const size_t hbytes = (size_t)BATCH * 512 * 4;          // 1 MiB
    float* h = (float*)d_ws;
    uint16_t* feats = (uint16_t*)((char*)d_ws + hbytes + 256);

    // smallest chunk count whose feats buffer fits ws
    const int cand[6] = {1, 2, 4, 8, 16, 32};
    int chunks = 32;
    for (int idx = 0; idx < 6; ++idx) {
        int c = cand[idx];
        long long kc = ((K_TOT + 64LL * c - 1) / (64LL * c)) * 64LL;
        if (hbytes + 256 + (size_t)(BATCH * kc * 2) <= ws_size) { chunks = c; break; }
    }
    const int Kc = (int)(((K_TOT + 64LL * chunks - 1) / (64LL * chunks)) * 64LL);

    hipMemsetAsync(h, 0, hbytes, stream);
    hipMemsetAsync(out, 0, (size_t)out_size * 4, stream);

    for (int layer = 0; layer < 2; ++layer) {
        const float* src = layer ? h  : x;
        const float* Wl  = layer ? W1 : W0;
        const float* bl  = layer ? b1 : b0;
        float*       Cl  = layer ? out : h;
        const int N = layer ? 256 : 512;
        const int S = layer ? 128 : 64;   // grid = (N/128) * S = 256 blocks
        for (int c = 0; c < chunks; ++c) {
            int k0 = c * Kc;
            int ext = K_TOT - k0 < Kc ? K_TOT - k0 : Kc;
            if (ext <= 0) break;
            featgen<<<514, 256, 0, stream>>>(src, feats, k0, ext, Kc);
            int steps = ext / BK;
            int ss = (steps + S - 1) / S;
            gemm_split<<<dim3(N / BN, S), 1024, 0, stream>>>(
                feats, Kc, Wl, k0, ext, Cl, N, bl, c == 0, ss);
        }
    }
}

// Round 2
// 581.275 us; speedup vs baseline: 1.4782x; 1.4782x over previous
//
#include <hip/hip_runtime.h>
#include <hip/hip_bf16.h>
#include <stdint.h>

// CubicModel: out = feats(feats(x)@W0^T + b0)@W1^T + b1
// feats(v) = [v, v_i*v_j (i<=j upper-tri row-major), v^3], d=512, K=132352
//
// R2: featgen rewritten as flat (b, k-group) map with 16B vector stores.
//     (R1 featgen was 315us at 6% HBM BW: serial-batch loop + scalar 2B stores.)

#define D_IN      512
#define BATCH     512
#define K_TOT     132352
#define QUAD_BASE 512
#define CUBE_BASE 131840
#define BN        128
#define BK        32

typedef __attribute__((ext_vector_type(8))) __bf16 bf16x8;
typedef __attribute__((ext_vector_type(4))) float  f32x4;

__device__ __forceinline__ uint16_t f2bf(float f) {
    union { float f; uint32_t u; } v; v.f = f;
    uint32_t u = v.u;
    return (uint16_t)((u + 0x7FFFu + ((u >> 16) & 1u)) >> 16);   // RNE
}

// ---------------- feature generation ----------------
// one thread = 8 contiguous feature cols of one batch row; 16B store.
// grid = (ceil(ext/8/256), BATCH). Region bounds 512 and 131840 are %8==0,
// so a group never straddles regions (k0 is %64==0).
__global__ __launch_bounds__(256) void featgen(const float* __restrict__ src,
                                               uint16_t* __restrict__ dst,
                                               int k0, int ext, int ldd)
{
    const int g = blockIdx.x * 256 + threadIdx.x;   // group index in window
    const int kloc = g * 8;
    if (kloc >= ext) return;
    const int b = blockIdx.y;
    const int k = k0 + kloc;
    const float* row = src + (size_t)b * D_IN;

    float v[8];
    if (k < QUAD_BASE) {                 // linear
        #pragma unroll
        for (int e = 0; e < 8; ++e) v[e] = row[k + e];
    } else if (k >= CUBE_BASE) {         // cube
        #pragma unroll
        for (int e = 0; e < 8; ++e) { float xv = row[k - CUBE_BASE + e]; v[e] = xv * xv * xv; }
    } else {                             // quad: decode q -> (i,j), walk 8
        const int q = k - QUAD_BASE;
        // base_i = i*(1025-i)/2; disc = 1050625-8q = (1025-2i)^2 at boundaries,
        // both < 2^24 -> float-exact; fixup +-1 for in-row rounding.
        float s = sqrtf((float)(1050625 - 8 * q));
        int i = (int)((1025.0f - s) * 0.5f);
        i = i < 0 ? 0 : (i > 511 ? 511 : i);
        while (i < 511 && (i + 1) * (1025 - (i + 1)) / 2 <= q) ++i;
        while (i > 0 && i * (1025 - i) / 2 > q) --i;
        int j = i + (q - i * (1025 - i) / 2);
        #pragma unroll
        for (int e = 0; e < 8; ++e) {
            v[e] = row[i] * row[j];
            if (++j == 512) { ++i; j = i; }
        }
    }

    uint32_t p0 = (uint32_t)f2bf(v[0]) | ((uint32_t)f2bf(v[1]) << 16);
    uint32_t p1 = (uint32_t)f2bf(v[2]) | ((uint32_t)f2bf(v[3]) << 16);
    uint32_t p2 = (uint32_t)f2bf(v[4]) | ((uint32_t)f2bf(v[5]) << 16);
    uint32_t p3 = (uint32_t)f2bf(v[6]) | ((uint32_t)f2bf(v[7]) << 16);
    uint4 pk; pk.x = p0; pk.y = p1; pk.z = p2; pk.w = p3;
    *(uint4*)(dst + (size_t)b * ldd + kloc) = pk;
}

// ---------------- split-K GEMM ----------------
// C[512][ldc] += A_bf16[512][lda(window kext)] * W_f32[n][K_TOT]^T  (+bias once)
// grid = (N/BN, S). 1024 threads = 16 waves, 8(m) x 2(n), wave tile 64x64.
__global__ __launch_bounds__(1024) void gemm_split(
    const uint16_t* __restrict__ A, int lda,
    const float* __restrict__ W, int k0, int kext,
    float* __restrict__ C, int ldc,
    const float* __restrict__ bias, int addbias, int split_steps)
{
    __shared__ uint16_t Al[512 * BK];   // 32 KiB  [row][k]
    __shared__ uint16_t Bl[BN * BK];    //  8 KiB  [n][k]

    const int tid  = threadIdx.x;
    const int lane = tid & 63;
    const int wave = tid >> 6;          // 0..15
    const int wm   = wave >> 1;         // 0..7 : rows wm*64
    const int wn   = wave & 1;          // 0..1 : cols wn*64
    const int n0   = blockIdx.x * BN;
    const int ks   = blockIdx.y;

    const int kbeg = ks * split_steps * BK;
    const int kend = min(kext, kbeg + split_steps * BK);
    if (kbeg >= kend) return;           // ks==0 always has work -> bias safe

    f32x4 acc[4][4] = {};

    const int fr = lane & 15;           // fragment row (A:m, B:n)
    const int fk = (lane >> 4) * 8;     // fragment k offset

    for (int kk = kbeg; kk < kend; kk += BK) {
        __syncthreads();
        // stage A: 512 rows x 32 bf16 (64B/row = 4 x 16B granules), 2048 granules
        #pragma unroll
        for (int it = 0; it < 2; ++it) {
            int g = it * 1024 + tid;
            int row = g >> 2, kq = (g & 3) * 8;
            uint4 v = *(const uint4*)(A + (size_t)row * lda + kk + kq);
            *(uint4*)(&Al[row * BK + kq]) = v;
        }
        // stage B: 128 rows x 32 f32 -> bf16, 1024 granules of 4 floats
        {
            int row = tid >> 3, kq = (tid & 7) * 4;
            const float* wp = W + (size_t)(n0 + row) * K_TOT + k0 + kk + kq;
            float4 w4 = *(const float4*)wp;
            ushort4 h4;
            h4.x = f2bf(w4.x); h4.y = f2bf(w4.y); h4.z = f2bf(w4.z); h4.w = f2bf(w4.w);
            *(ushort4*)(&Bl[row * BK + kq]) = h4;
        }
        __syncthreads();

        bf16x8 a[4];
        #pragma unroll
        for (int mf = 0; mf < 4; ++mf)
            a[mf] = *(const bf16x8*)(&Al[(wm * 64 + mf * 16 + fr) * BK + fk]);
        #pragma unroll
        for (int nf = 0; nf < 4; ++nf) {
            bf16x8 b = *(const bf16x8*)(&Bl[(wn * 64 + nf * 16 + fr) * BK + fk]);
            #pragma unroll
            for (int mf = 0; mf < 4; ++mf)
                acc[mf][nf] = __builtin_amdgcn_mfma_f32_16x16x32_bf16(a[mf], b, acc[mf][nf], 0, 0, 0);
        }
    }

    // epilogue: C/D layout col=lane&15, row=(lane>>4)*4+reg  [m89-verified]
    const bool dob = (addbias != 0) && (ks == 0);
    const int rbase = wm * 64 + (lane >> 4) * 4;
    const int cbase = n0 + wn * 64 + (lane & 15);
    #pragma unroll
    for (int nf = 0; nf < 4; ++nf) {
        const int col = cbase + nf * 16;
        const float bv = dob ? bias[col] : 0.0f;
        #pragma unroll
        for (int mf = 0; mf < 4; ++mf) {
            const int row = rbase + mf * 16;
            #pragma unroll
            for (int r = 0; r < 4; ++r)
                unsafeAtomicAdd(&C[(size_t)(row + r) * ldc + col], acc[mf][nf][r] + bv);
        }
    }
}

// ---------------- host ----------------
extern "C" void kernel_launch(void* const* d_in, const int* in_sizes, int n_in,
                              void* d_out, int out_size, void* d_ws, size_t ws_size,
                              hipStream_t stream)
{
    const float* x  = (const float*)d_in[0];
    const float* W0 = (const float*)d_in[1];
    const float* b0 = (const float*)d_in[2];
    const float* W1 = (const float*)d_in[3];
    const float* b1 = (const float*)d_in[4];
    float* out = (float*)d_out;

    const size_t hbytes = (size_t)BATCH * 512 * 4;          // 1 MiB
    float* h = (float*)d_ws;
    uint16_t* feats = (uint16_t*)((char*)d_ws + hbytes + 256);

    // smallest chunk count whose feats buffer fits ws
    const int cand[6] = {1, 2, 4, 8, 16, 32};
    int chunks = 32;
    for (int idx = 0; idx < 6; ++idx) {
        int c = cand[idx];
        long long kc = ((K_TOT + 64LL * c - 1) / (64LL * c)) * 64LL;
        if (hbytes + 256 + (size_t)(BATCH * kc * 2) <= ws_size) { chunks = c; break; }
    }
    const int Kc = (int)(((K_TOT + 64LL * chunks - 1) / (64LL * chunks)) * 64LL);

    hipMemsetAsync(h, 0, hbytes, stream);
    hipMemsetAsync(out, 0, (size_t)out_size * 4, stream);

    for (int layer = 0; layer < 2; ++layer) {
        const float* src = layer ? h  : x;
        const float* Wl  = layer ? W1 : W0;
        const float* bl  = layer ? b1 : b0;
        float*       Cl  = layer ? out : h;
        const int N = layer ? 256 : 512;
        const int S = layer ? 128 : 64;   // grid = (N/128) * S = 256 blocks
        for (int c = 0; c < chunks; ++c) {
            int k0 = c * Kc;
            int ext = K_TOT - k0 < Kc ? K_TOT - k0 : Kc;
            if (ext <= 0) break;
            int gpr = ext / 8;                       // 16B groups per row
            featgen<<<dim3((gpr + 255) / 256, BATCH), 256, 0, stream>>>(src, feats, k0, ext, Kc);
            int steps = ext / BK;
            int ss = (steps + S - 1) / S;
            gemm_split<<<dim3(N / BN, S), 1024, 0, stream>>>(
                feats, Kc, Wl, k0, ext, Cl, N, bl, c == 0, ss);
        }
    }
}

// Round 3
// 529.835 us; speedup vs baseline: 1.6217x; 1.0971x over previous
//
#include <hip/hip_runtime.h>
#include <hip/hip_bf16.h>
#include <stdint.h>

// CubicModel: out = feats(feats(x)@W0^T + b0)@W1^T + b1
// feats(v) = [v, v_i*v_j (i<=j), v^3], d=512, K=132352
//
// R3: GEMM rebuilt: BK=64, XOR-swizzled LDS (conflict-free reads+writes),
//     A via global_load_lds (pre-swizzled source) double-buffered,
//     B (f32 W) reg-staged one step ahead, raw s_barrier + counted vmcnt.
//     (R2 gemm: 9200 cyc/step = exposed latency + 8-way LDS conflicts.)

#define D_IN      512
#define BATCH     512
#define K_TOT     132352
#define QUAD_BASE 512
#define CUBE_BASE 131840
#define BM        512
#define BN        128
#define BK        64          // row = 128 B in LDS

typedef __attribute__((ext_vector_type(8))) __bf16 bf16x8;
typedef __attribute__((ext_vector_type(4))) float  f32x4;

__device__ __forceinline__ uint32_t f2bf(float f) {
    union { float f; uint32_t u; } v; v.f = f;
    uint32_t u = v.u;
    return (u + 0x7FFFu + ((u >> 16) & 1u)) >> 16;   // RNE
}

// ---------------- feature generation (R2, unchanged) ----------------
__global__ __launch_bounds__(256) void featgen(const float* __restrict__ src,
                                               uint16_t* __restrict__ dst,
                                               int k0, int ext, int ldd)
{
    const int g = blockIdx.x * 256 + threadIdx.x;
    const int kloc = g * 8;
    if (kloc >= ext) return;
    const int b = blockIdx.y;
    const int k = k0 + kloc;
    const float* row = src + (size_t)b * D_IN;

    float v[8];
    if (k < QUAD_BASE) {
        #pragma unroll
        for (int e = 0; e < 8; ++e) v[e] = row[k + e];
    } else if (k >= CUBE_BASE) {
        #pragma unroll
        for (int e = 0; e < 8; ++e) { float xv = row[k - CUBE_BASE + e]; v[e] = xv * xv * xv; }
    } else {
        const int q = k - QUAD_BASE;
        float s = sqrtf((float)(1050625 - 8 * q));
        int i = (int)((1025.0f - s) * 0.5f);
        i = i < 0 ? 0 : (i > 511 ? 511 : i);
        while (i < 511 && (i + 1) * (1025 - (i + 1)) / 2 <= q) ++i;
        while (i > 0 && i * (1025 - i) / 2 > q) --i;
        int j = i + (q - i * (1025 - i) / 2);
        #pragma unroll
        for (int e = 0; e < 8; ++e) {
            v[e] = row[i] * row[j];
            if (++j == 512) { ++i; j = i; }
        }
    }
    uint4 pk;
    pk.x = f2bf(v[0]) | (f2bf(v[1]) << 16);
    pk.y = f2bf(v[2]) | (f2bf(v[3]) << 16);
    pk.z = f2bf(v[4]) | (f2bf(v[5]) << 16);
    pk.w = f2bf(v[6]) | (f2bf(v[7]) << 16);
    *(uint4*)(dst + (size_t)b * ldd + kloc) = pk;
}

// ---------------- GEMM ----------------
// C[512][ldc] += A_bf16[512][lda] * W_f32[n][K_TOT]^T (+bias once)
// 1024 thr = 16 waves (8m x 2n), wave tile 64x64, mfma 16x16x32, acc 4x4.
// LDS: A dbuf 2x64KB + B 16KB = 144KB dynamic. Swizzle: 16B chunk c of row r
// stored at chunk (c ^ (r&7)) -> reads & writes conflict-free.
__global__ __launch_bounds__(1024, 1) void gemm_bt(
    const uint16_t* __restrict__ A, int lda,
    const float* __restrict__ W, int k0, int kext,
    float* __restrict__ C, int ldc,
    const float* __restrict__ bias, int addbias, int split_steps)
{
    extern __shared__ uint8_t smem[];          // [0,64K)=A0 [64K,128K)=A1 [128K,144K)=B
    uint8_t* const Bb = smem + 131072;

    const int tid  = threadIdx.x;
    const int lane = tid & 63;
    const int wave = tid >> 6;
    const int wm   = wave >> 1;                // 0..7
    const int wn   = wave & 1;                 // 0..1
    const int n0   = blockIdx.x * BN;
    const int ks   = blockIdx.y;

    const int kbeg = ks * split_steps * BK;
    const int kend = min(kext, kbeg + split_steps * BK);
    if (kbeg >= kend) return;                  // ks==0 always has work -> bias safe
    const int nt = (kend - kbeg) / BK;

    // A staging geometry: granule L=(i*16+wave)*64+lane; row=L>>3, cpos=L&7,
    // source chunk = cpos ^ (row&7)  (pre-swizzled global, linear LDS dest)
    const int aL    = wave * 64 + lane;        // i term added per issue
    // B staging: thread -> (row=tid>>3, chunk=tid&7), 8 f32 -> 1 swizzled b128
    const int brow   = tid >> 3;
    const int bchunk = tid & 7;
    const float* const wsrc = W + (size_t)(n0 + brow) * K_TOT + k0 + bchunk * 8;
    const uint32_t bdst = (uint32_t)brow * 128 + (uint32_t)((bchunk ^ (brow & 7)) * 16);

#define ISSUE_A(bufoff, kkv)                                                        \
    do {                                                                            \
        _Pragma("unroll")                                                           \
        for (int i_ = 0; i_ < 4; ++i_) {                                            \
            int L_ = i_ * 1024 + aL;                                                \
            int r_ = L_ >> 3;                                                       \
            int c_ = (L_ & 7) ^ (r_ & 7);                                           \
            const uint16_t* g_ = A + (size_t)r_ * lda + (kkv) + c_ * 8;             \
            __builtin_amdgcn_global_load_lds(                                       \
                (const __attribute__((address_space(1))) void*)g_,                  \
                (__attribute__((address_space(3))) void*)(smem + (bufoff) +         \
                    (size_t)(i_ * 16 + wave) * 1024),                               \
                16, 0, 0);                                                          \
        }                                                                           \
    } while (0)

    // prologue: B(0) regs + A(0) -> buf0
    float4 bv0 = *(const float4*)(wsrc + kbeg);
    float4 bv1 = *(const float4*)(wsrc + kbeg + 4);
    ISSUE_A(0, kbeg);

    f32x4 acc[4][4] = {};
    const int fr = lane & 15;
    const int h  = lane >> 4;                  // 16B chunk within K=32 sub-step

    for (int t = 0; t < nt; ++t) {
        const int kk = kbeg + t * BK;
        const uint32_t cur = (uint32_t)(t & 1) * 65536u;
        const uint32_t nxt = cur ^ 65536u;

        // pack B(t) (compiler waits its own bv loads here; A-prefetch had a
        // full compute phase to land, so this wait is ~free)
        uint4 pk;
        pk.x = f2bf(bv0.x) | (f2bf(bv0.y) << 16);
        pk.y = f2bf(bv0.z) | (f2bf(bv0.w) << 16);
        pk.z = f2bf(bv1.x) | (f2bf(bv1.y) << 16);
        pk.w = f2bf(bv1.z) | (f2bf(bv1.w) << 16);

        __builtin_amdgcn_s_barrier();          // prev compute done: Bb & A[nxt] free
        asm volatile("" ::: "memory");

        *(uint4*)(Bb + bdst) = pk;             // swizzled, conflict-free

        const int kkn = (t + 1 < nt) ? kk + BK : kk;   // clamped prefetch
        ISSUE_A(nxt, kkn);
        bv0 = *(const float4*)(wsrc + kkn);
        bv1 = *(const float4*)(wsrc + kkn + 4);

        asm volatile("s_waitcnt lgkmcnt(0)" ::: "memory");  // Bb write drained
        asm volatile("s_waitcnt vmcnt(6)" ::: "memory");    // A(t) in LDS; 6 newer fly
        __builtin_amdgcn_sched_barrier(0);
        __builtin_amdgcn_s_barrier();          // Bb + A(t) visible to all
        asm volatile("" ::: "memory");

        const uint8_t* const Ab = smem + cur;
        #pragma unroll
        for (int s = 0; s < 2; ++s) {
            bf16x8 a[4];
            #pragma unroll
            for (int mf = 0; mf < 4; ++mf) {
                int row = wm * 64 + mf * 16 + fr;
                a[mf] = *(const bf16x8*)(Ab + row * 128 + (((s * 4 + h) ^ (row & 7)) * 16));
            }
            #pragma unroll
            for (int nf = 0; nf < 4; ++nf) {
                int row = wn * 64 + nf * 16 + fr;
                bf16x8 b = *(const bf16x8*)(Bb + row * 128 + (((s * 4 + h) ^ (row & 7)) * 16));
                #pragma unroll
                for (int mf = 0; mf < 4; ++mf)
                    acc[mf][nf] = __builtin_amdgcn_mfma_f32_16x16x32_bf16(a[mf], b, acc[mf][nf], 0, 0, 0);
            }
        }
    }
#undef ISSUE_A

    // epilogue: C/D layout col=lane&15, row=(lane>>4)*4+reg  [m89-verified]
    const bool dob = (addbias != 0) && (ks == 0);
    const int rbase = wm * 64 + (lane >> 4) * 4;
    const int cbase = n0 + wn * 64 + (lane & 15);
    #pragma unroll
    for (int nf = 0; nf < 4; ++nf) {
        const int col = cbase + nf * 16;
        const float bv = dob ? bias[col] : 0.0f;
        #pragma unroll
        for (int mf = 0; mf < 4; ++mf) {
            const int row = rbase + mf * 16;
            #pragma unroll
            for (int r = 0; r < 4; ++r)
                unsafeAtomicAdd(&C[(size_t)(row + r) * ldc + col], acc[mf][nf][r] + bv);
        }
    }
}

// ---------------- host ----------------
extern "C" void kernel_launch(void* const* d_in, const int* in_sizes, int n_in,
                              void* d_out, int out_size, void* d_ws, size_t ws_size,
                              hipStream_t stream)
{
    const float* x  = (const float*)d_in[0];
    const float* W0 = (const float*)d_in[1];
    const float* b0 = (const float*)d_in[2];
    const float* W1 = (const float*)d_in[3];
    const float* b1 = (const float*)d_in[4];
    float* out = (float*)d_out;

    const size_t hbytes = (size_t)BATCH * 512 * 4;
    float* h = (float*)d_ws;
    uint16_t* feats = (uint16_t*)((char*)d_ws + hbytes + 256);

    const int cand[6] = {1, 2, 4, 8, 16, 32};
    int chunks = 32;
    for (int idx = 0; idx < 6; ++idx) {
        int c = cand[idx];
        long long kc = ((K_TOT + 64LL * c - 1) / (64LL * c)) * 64LL;
        if (hbytes + 256 + (size_t)(BATCH * kc * 2) <= ws_size) { chunks = c; break; }
    }
    const int Kc = (int)(((K_TOT + 64LL * chunks - 1) / (64LL * chunks)) * 64LL);

    static int lds_set = 0;
    if (!lds_set) {   // host-side, not stream-ordered; idempotent & deterministic
        hipFuncSetAttribute((const void*)gemm_bt,
                            hipFuncAttributeMaxDynamicSharedMemorySize, 147456);
        lds_set = 1;
    }

    hipMemsetAsync(h, 0, hbytes, stream);
    hipMemsetAsync(out, 0, (size_t)out_size * 4, stream);

    for (int layer = 0; layer < 2; ++layer) {
        const float* src = layer ? h  : x;
        const float* Wl  = layer ? W1 : W0;
        const float* bl  = layer ? b1 : b0;
        float*       Cl  = layer ? out : h;
        const int N = layer ? 256 : 512;
        const int S = layer ? 128 : 64;        // grid = (N/128)*S = 256 blocks
        for (int c = 0; c < chunks; ++c) {
            int k0 = c * Kc;
            int ext = K_TOT - k0 < Kc ? K_TOT - k0 : Kc;
            if (ext <= 0) break;
            featgen<<<dim3((ext / 8 + 255) / 256, BATCH), 256, 0, stream>>>(src, feats, k0, ext, Kc);
            int steps = ext / BK;
            int ss = (steps + S - 1) / S;
            gemm_bt<<<dim3(N / BN, S), 1024, 147456, stream>>>(
                feats, Kc, Wl, k0, ext, Cl, N, bl, c == 0, ss);
        }
    }
}